// Round 3
// baseline (503.479 us; speedup 1.0000x reference)
//
#include <hip/hip_runtime.h>
#include <hip/hip_cooperative_groups.h>
#include <math.h>

namespace cg = cooperative_groups;

#define BB 4
#define SS 16384
#define NN 1024
#define DD 64
#define MW 32    // mask words per row = NN/32
#define CAP 256  // bucket capacity per (b,node); Poisson(16) => overflow P ~ 0
#define NBLK 512
#define NTHR 256
#define RPW 2    // rows per wave: 4096 rows / (512 blk * 4 waves)

__device__ __forceinline__ float wave_sum(float v) {
    #pragma unroll
    for (int off = 32; off > 0; off >>= 1) v += __shfl_xor(v, off, 64);
    return v;
}
__device__ __forceinline__ float wave_max(float v) {
    #pragma unroll
    for (int off = 32; off > 0; off >>= 1) v = fmaxf(v, __shfl_xor(v, off, 64));
    return v;
}
__device__ __forceinline__ int wave_sum_i(int v) {
    #pragma unroll
    for (int off = 32; off > 0; off >>= 1) v += __shfl_xor(v, off, 64);
    return v;
}

// Single cooperative kernel: zero -> build -> gather/transform -> attention.
// count and mask MUST be contiguous (mask == (uint*)(count + BB*NN)).
__global__ __launch_bounds__(NTHR, 2) void fused_kernel(
        const float* __restrict__ ff, const int* __restrict__ src_ips,
        const int* __restrict__ dst_ips, const float* __restrict__ W,
        const float* __restrict__ a1, const float* __restrict__ a2,
        int* __restrict__ count, unsigned int* __restrict__ mask,
        int* __restrict__ bucket, float* __restrict__ Wh,
        float* __restrict__ f1, float* __restrict__ f2,
        float* __restrict__ out) {
    cg::grid_group grid = cg::this_grid();
    __shared__ float Ws[DD * DD];
    __shared__ float a1s[DD], a2s[DD];
    int t = threadIdx.x;
    int gtid = blockIdx.x * NTHR + t;
    int wid = gtid >> 6, lane = gtid & 63;

    // LDS fill for phase 2 (grid.sync after phase 1 doubles as the barrier)
    for (int i = t; i < DD * DD; i += NTHR) Ws[i] = W[i];
    if (t < DD) { a1s[t] = a1[t]; a2s[t] = a2[t]; }

    // ---- phase 0: zero count (BB*NN ints) + mask (BB*NN*MW words), contiguous
    for (int i = gtid; i < BB * NN * (MW + 1); i += NBLK * NTHR)
        count[i] = 0;
    __threadfence();
    grid.sync();
    __threadfence();

    // ---- phase 1: bucket flows by (b,dst); set symmetric adjacency bits
    if (gtid < BB * SS) {
        int b   = gtid >> 14;                    // SS = 2^14
        int dst = dst_ips[gtid];
        int src = src_ips[gtid];
        int row = (b << 10) + dst;
        int pos = atomicAdd(count + row, 1);
        if (pos < CAP) bucket[row * CAP + pos] = gtid;
        unsigned int* mb = mask + (size_t)b * NN * MW;
        atomicOr(mb + src * MW + (dst >> 5), 1u << (dst & 31));
        atomicOr(mb + dst * MW + (src >> 5), 1u << (src & 31));
    }
    __threadfence();
    grid.sync();
    __threadfence();

    // ---- phase 2: per row: gather-sum, normalize, Wh = h@W, f1, f2
    for (int rr = 0; rr < RPW; ++rr) {
        int row = wid * RPW + rr;                // [0, BB*NN)
        int cnt = min(count[row], CAP);
        const int* bk = bucket + (size_t)row * CAP;
        float acc = 0.f;
        for (int base = 0; base < cnt; base += 64) {
            int fid = (base + lane < cnt) ? bk[base + lane] : 0;
            int lim = min(64, cnt - base);
            for (int i = 0; i < lim; ++i) {
                int flow = __shfl(fid, i, 64);
                acc += ff[(size_t)flow * DD + lane];
            }
        }
        float nrm = fmaxf(sqrtf(wave_sum(acc * acc)), 1e-12f);
        float h = acc / nrm;
        float whl = 0.f;
        #pragma unroll
        for (int k = 0; k < DD; ++k)
            whl = fmaf(__shfl(h, k, 64), Ws[k * DD + lane], whl);
        Wh[row * DD + lane] = whl;
        float p1 = wave_sum(whl * a1s[lane]);
        float p2 = wave_sum(whl * a2s[lane]);
        if (lane == 0) { f1[row] = p1; f2[row] = p2; }
    }
    __threadfence();
    grid.sync();
    __threadfence();

    // ---- phase 3: sparse masked softmax + elu(attn @ Wh)
    for (int rr = 0; rr < RPW; ++rr) {
        int row = wid * RPW + rr;                // [0, BB*NN)
        int b = row >> 10;
        unsigned int mw = mask[(size_t)row * MW + (lane & 31)];  // lanes 32-63 dup
        const float* f2b = f2 + b * NN;
        const float* Whb = Wh + (size_t)(b << 10) * DD;
        float f1i = f1[row];
        int cnt = wave_sum_i(lane < MW ? __popc(mw) : 0);

        // scores: j = lane + tt*64; word idx = tt*2 + (lane>>5), bit = lane&31
        float ev[16];
        float m = -INFINITY;
        #pragma unroll
        for (int tt = 0; tt < 16; ++tt) {
            unsigned int wv = __shfl(mw, (tt << 1) + (lane >> 5), 64);
            ev[tt] = -INFINITY;
            if (wv & (1u << (lane & 31))) {
                int j = lane + (tt << 6);
                float e = f1i + f2b[j];
                ev[tt] = (e >= 0.f) ? e : 0.2f * e;
                m = fmaxf(m, ev[tt]);
            }
        }
        m = wave_max(m);
        float lsum = 0.f;
        #pragma unroll
        for (int tt = 0; tt < 16; ++tt)
            if (ev[tt] > -INFINITY) lsum += __expf(ev[tt] - m);
        lsum = wave_sum(lsum);

        float acc = 0.f;
        if (cnt > 0) {
            for (int w = 0; w < MW; ++w) {
                unsigned int bits = __shfl(mw, w, 64);
                while (bits) {
                    int j = (w << 5) + (__ffs(bits) - 1);
                    bits &= bits - 1;
                    float e = f1i + f2b[j];
                    e = (e >= 0.f) ? e : 0.2f * e;
                    acc = fmaf(__expf(e - m), Whb[j * DD + lane], acc);
                }
            }
            acc /= lsum;
        } else {
            // all-masked row: softmax of uniform NEG_BIG = 1/N over ALL j
            for (int j = 0; j < NN; ++j) acc += Whb[j * DD + lane];
            acc *= (1.f / NN);
        }
        out[row * DD + lane] = (acc > 0.f) ? acc : expm1f(acc);
    }
}

extern "C" void kernel_launch(void* const* d_in, const int* in_sizes, int n_in,
                              void* d_out, int out_size, void* d_ws, size_t ws_size,
                              hipStream_t stream) {
    const float* ff      = (const float*)d_in[0];
    const int*   src_ips = (const int*)d_in[1];
    const int*   dst_ips = (const int*)d_in[2];
    // d_in[3] flow_volumes, d_in[4] emb, d_in[5..8] MLP params: adj weights are
    // products of sigmoids => strictly positive => only the >0 mask matters.
    const float* W  = (const float*)d_in[9];
    const float* a1 = (const float*)d_in[10];
    const float* a2 = (const float*)d_in[11];
    float* out = (float*)d_out;

    char* ws = (char*)d_ws;
    int* count         = (int*)ws;                           // 16 KB
    unsigned int* mask = (unsigned int*)(ws + (16 << 10));   // 512 KB (contig!)
    float* f1          = (float*)(ws + (528 << 10));         // 16 KB
    float* f2          = (float*)(ws + (544 << 10));         // 16 KB
    int* bucket        = (int*)(ws + (1 << 20));             // 4 MB
    float* Wh          = (float*)(ws + (5 << 20));           // 1 MB

    void* args[] = { &ff, &src_ips, &dst_ips, &W, &a1, &a2,
                     &count, &mask, &bucket, &Wh, &f1, &f2, &out };
    hipLaunchCooperativeKernel((void*)fused_kernel, dim3(NBLK), dim3(NTHR),
                               args, 0, stream);
}

// Round 4
// 118.161 us; speedup vs baseline: 4.2610x; 4.2610x over previous
//
#include <hip/hip_runtime.h>
#include <math.h>

#define BB 4
#define SS 16384
#define NN 1024
#define DD 64
#define MW 32    // mask words per row = NN/32
#define CAP 256  // bucket capacity per (b,node); Poisson(16) => overflow P ~ 0

__device__ __forceinline__ float wave_sum(float v) {
    #pragma unroll
    for (int off = 32; off > 0; off >>= 1) v += __shfl_xor(v, off, 64);
    return v;
}
__device__ __forceinline__ float wave_max(float v) {
    #pragma unroll
    for (int off = 32; off > 0; off >>= 1) v = fmaxf(v, __shfl_xor(v, off, 64));
    return v;
}
__device__ __forceinline__ int wave_sum_i(int v) {
    #pragma unroll
    for (int off = 32; off > 0; off >>= 1) v += __shfl_xor(v, off, 64);
    return v;
}

// 1 thread per flow: bucket the flow id by (b,dst), set symmetric adj bits.
__global__ __launch_bounds__(256) void build_kernel(
        const int* __restrict__ src_ips, const int* __restrict__ dst_ips,
        int* __restrict__ count, int* __restrict__ bucket,
        unsigned int* __restrict__ mask) {
    int tid = blockIdx.x * 256 + threadIdx.x;   // global flow id, [0, BB*SS)
    int b   = tid >> 14;                        // SS = 2^14
    int dst = dst_ips[tid];
    int src = src_ips[tid];
    int row = (b << 10) + dst;
    int pos = atomicAdd(count + row, 1);
    if (pos < CAP) bucket[row * CAP + pos] = tid;
    unsigned int* mb = mask + (size_t)b * NN * MW;
    atomicOr(mb + src * MW + (dst >> 5), 1u << (dst & 31));
    atomicOr(mb + dst * MW + (src >> 5), 1u << (src & 31));
}

// One wave per (b,node): float4 gather-sum of flow rows, normalize, h@W, f1, f2.
// Lane l handles flow-slot (l>>4) and float4 index (l&15): each iteration the
// wave reads 4 complete 256B flow rows as coalesced 16B loads.
__global__ __launch_bounds__(256) void gather_transform_kernel(
        const float* __restrict__ ff, const int* __restrict__ count,
        const int* __restrict__ bucket, const float* __restrict__ W,
        const float* __restrict__ a1, const float* __restrict__ a2,
        float* __restrict__ Wh, float* __restrict__ f1, float* __restrict__ f2) {
    __shared__ float Ws[DD * DD];
    __shared__ float hs[4][DD];
    __shared__ float a1s[DD], a2s[DD];
    int t = threadIdx.x;
    for (int i = t; i < DD * DD; i += 256) Ws[i] = W[i];
    if (t < DD) { a1s[t] = a1[t]; a2s[t] = a2[t]; }
    int wave = t >> 6, lane = t & 63;
    int fq = lane >> 4;                         // flow slot 0..3
    int qi = lane & 15;                         // float4 index within row
    int row = blockIdx.x * 4 + wave;            // [0, BB*NN)

    int cnt = min(count[row], CAP);
    const int* bk = bucket + (size_t)row * CAP;
    float4 v = make_float4(0.f, 0.f, 0.f, 0.f);
    for (int base = 0; base < cnt; base += 4) {
        int fi = base + fq;
        if (fi < cnt) {
            int flow = bk[fi];                  // 4 distinct addrs, broadcast x16
            float4 x = ((const float4*)(ff + (size_t)flow * DD))[qi];
            v.x += x.x; v.y += x.y; v.z += x.z; v.w += x.w;
        }
    }
    // reduce across the 4 flow slots (xor 16 then 32 sums all fq groups)
    #pragma unroll
    for (int off = 16; off <= 32; off <<= 1) {
        v.x += __shfl_xor(v.x, off, 64);
        v.y += __shfl_xor(v.y, off, 64);
        v.z += __shfl_xor(v.z, off, 64);
        v.w += __shfl_xor(v.w, off, 64);
    }
    // sum of squares: every lane holds its feature-group sum replicated 4x
    float ssq = (fq == 0) ? (v.x*v.x + v.y*v.y + v.z*v.z + v.w*v.w) : 0.f;
    float nrm = fmaxf(sqrtf(wave_sum(ssq)), 1e-12f);
    float inv = 1.f / nrm;
    __syncthreads();                            // Ws/a1s/a2s ready
    if (fq == 0)
        ((float4*)hs[wave])[qi] = make_float4(v.x*inv, v.y*inv, v.z*inv, v.w*inv);
    // same-wave LDS write->read; compiler inserts the lgkmcnt wait
    float whl = 0.f;
    #pragma unroll
    for (int k = 0; k < DD; ++k)
        whl = fmaf(hs[wave][k], Ws[k * DD + lane], whl);
    Wh[row * DD + lane] = whl;
    float p1 = wave_sum(whl * a1s[lane]);
    float p2 = wave_sum(whl * a2s[lane]);
    if (lane == 0) { f1[row] = p1; f2[row] = p2; }
}

// One wave per output row i: sparse masked softmax over neighbors, then
// out[i] = elu(sum_j attn_ij * Wh[j]).  Softmax numerators cached in LDS.
__global__ __launch_bounds__(256) void attn_kernel(
        const unsigned int* __restrict__ mask, const float* __restrict__ f1,
        const float* __restrict__ f2, const float* __restrict__ Wh,
        float* __restrict__ out) {
    __shared__ unsigned int ms[4][MW];
    __shared__ float ps[4][NN];                 // exp(e-m), 0 where masked
    int t = threadIdx.x;
    int wave = t >> 6, lane = t & 63;
    int row = blockIdx.x * 4 + wave;            // [0, BB*NN)
    int b = row >> 10;
    const unsigned int* mrow = mask + (size_t)row * MW;
    if (lane < MW) ms[wave][lane] = mrow[lane];
    __syncthreads();
    const float* f2b = f2 + b * NN;
    const float* Whb = Wh + (size_t)(b << 10) * DD;
    float f1i = f1[row];

    int cnt = (lane < MW) ? __popc(ms[wave][lane]) : 0;
    cnt = wave_sum_i(cnt);

    // phase 1: leaky-relu scores (16 j's per lane), max, then exp into LDS
    float ev[16];
    float m = -INFINITY;
    #pragma unroll
    for (int tt = 0; tt < 16; ++tt) {
        int j = lane + (tt << 6);
        ev[tt] = -INFINITY;
        if (ms[wave][j >> 5] & (1u << (j & 31))) {
            float e = f1i + f2b[j];
            ev[tt] = (e >= 0.f) ? e : 0.2f * e;
            m = fmaxf(m, ev[tt]);
        }
    }
    m = wave_max(m);
    float lsum = 0.f;
    #pragma unroll
    for (int tt = 0; tt < 16; ++tt) {
        float p = (ev[tt] > -INFINITY) ? __expf(ev[tt] - m) : 0.f;
        ps[wave][lane + (tt << 6)] = p;
        lsum += p;
    }
    lsum = wave_sum(lsum);

    // phase 2: lane = feature; iterate set bits, numerators from LDS
    float acc = 0.f;
    if (cnt > 0) {
        for (int w = 0; w < MW; ++w) {
            unsigned int bits = ms[wave][w];
            while (bits) {
                int j = (w << 5) + (__ffs(bits) - 1);
                bits &= bits - 1;
                acc = fmaf(ps[wave][j], Whb[j * DD + lane], acc);
            }
        }
        acc /= lsum;
    } else {
        // all-masked row: softmax of uniform NEG_BIG = 1/N over ALL j
        for (int j = 0; j < NN; ++j) acc += Whb[j * DD + lane];
        acc *= (1.f / NN);
    }
    out[row * DD + lane] = (acc > 0.f) ? acc : expm1f(acc);
}

extern "C" void kernel_launch(void* const* d_in, const int* in_sizes, int n_in,
                              void* d_out, int out_size, void* d_ws, size_t ws_size,
                              hipStream_t stream) {
    const float* ff      = (const float*)d_in[0];
    const int*   src_ips = (const int*)d_in[1];
    const int*   dst_ips = (const int*)d_in[2];
    // d_in[3] flow_volumes, d_in[4] emb, d_in[5..8] MLP params: adj weights are
    // products of sigmoids => strictly positive => only the >0 mask matters.
    const float* W  = (const float*)d_in[9];
    const float* a1 = (const float*)d_in[10];
    const float* a2 = (const float*)d_in[11];
    float* out = (float*)d_out;

    char* ws = (char*)d_ws;
    int* count         = (int*)ws;                           // 16 KB
    unsigned int* mask = (unsigned int*)(ws + (16 << 10));   // 512 KB (contig!)
    float* f1          = (float*)(ws + (528 << 10));         // 16 KB
    float* f2          = (float*)(ws + (544 << 10));         // 16 KB
    int* bucket        = (int*)(ws + (1 << 20));             // 4 MB
    float* Wh          = (float*)(ws + (5 << 20));           // 1 MB

    // zero count + mask in one contiguous fill (they are adjacent)
    hipMemsetAsync(count, 0, (528 << 10), stream);

    build_kernel<<<BB * SS / 256, 256, 0, stream>>>(src_ips, dst_ips, count, bucket, mask);
    gather_transform_kernel<<<BB * NN / 4, 256, 0, stream>>>(ff, count, bucket, W, a1, a2, Wh, f1, f2);
    attn_kernel<<<BB * NN / 4, 256, 0, stream>>>(mask, f1, f2, Wh, out);
}

// Round 5
// 110.027 us; speedup vs baseline: 4.5760x; 1.0739x over previous
//
#include <hip/hip_runtime.h>
#include <math.h>

#define BB 4
#define SS 16384
#define NN 1024
#define DD 64
#define MW 32    // mask words per row = NN/32
#define CAP 256  // bucket capacity per (b,node); Poisson(16) => overflow P ~ 0
#define JCAP 256 // compact neighbor-list capacity per row (fallback if exceeded)

__device__ __forceinline__ float wave_sum(float v) {
    #pragma unroll
    for (int off = 32; off > 0; off >>= 1) v += __shfl_xor(v, off, 64);
    return v;
}
__device__ __forceinline__ float wave_max(float v) {
    #pragma unroll
    for (int off = 32; off > 0; off >>= 1) v = fmaxf(v, __shfl_xor(v, off, 64));
    return v;
}

// 1 thread per flow: bucket the flow id by (b,dst), set symmetric adj bits.
__global__ __launch_bounds__(256) void build_kernel(
        const int* __restrict__ src_ips, const int* __restrict__ dst_ips,
        int* __restrict__ count, int* __restrict__ bucket,
        unsigned int* __restrict__ mask) {
    int tid = blockIdx.x * 256 + threadIdx.x;   // global flow id, [0, BB*SS)
    int b   = tid >> 14;                        // SS = 2^14
    int dst = dst_ips[tid];
    int src = src_ips[tid];
    int row = (b << 10) + dst;
    int pos = atomicAdd(count + row, 1);
    if (pos < CAP) bucket[row * CAP + pos] = tid;
    unsigned int* mb = mask + (size_t)b * NN * MW;
    atomicOr(mb + src * MW + (dst >> 5), 1u << (dst & 31));
    atomicOr(mb + dst * MW + (src >> 5), 1u << (src & 31));
}

// One wave per (b,node): float4 gather-sum of flow rows, normalize, h@W, f1, f2.
// Bucket row preloaded into registers (1 coalesced load) so the per-iteration
// chain is just shfl -> ff float4 load. Lane l: flow-slot l>>4, float4 l&15.
__global__ __launch_bounds__(256) void gather_transform_kernel(
        const float* __restrict__ ff, const int* __restrict__ count,
        const int* __restrict__ bucket, const float* __restrict__ W,
        const float* __restrict__ a1, const float* __restrict__ a2,
        float* __restrict__ Wh, float* __restrict__ f1, float* __restrict__ f2) {
    __shared__ float Ws[DD * DD];
    __shared__ float hs[4][DD];
    __shared__ float a1s[DD], a2s[DD];
    int t = threadIdx.x;
    for (int i = t; i < DD * DD / 4; i += 256)
        ((float4*)Ws)[i] = ((const float4*)W)[i];
    if (t < DD) { a1s[t] = a1[t]; a2s[t] = a2[t]; }
    int wave = t >> 6, lane = t & 63;
    int fq = lane >> 4;                         // flow slot 0..3
    int qi = lane & 15;                         // float4 index within row
    int row = blockIdx.x * 4 + wave;            // [0, BB*NN)

    int cnt = min(count[row], CAP);
    const int* bk = bucket + (size_t)row * CAP;
    int bkreg = (lane < cnt) ? bk[lane] : 0;    // whole bucket row, 1 load
    float4 v = make_float4(0.f, 0.f, 0.f, 0.f);
    int lim = min(cnt, 64);
    for (int base = 0; base < lim; base += 4) {
        int fi = base + fq;                     // <= 63 always here
        int flow = __shfl(bkreg, fi, 64);
        if (fi < lim) {
            float4 x = ((const float4*)(ff + (size_t)flow * DD))[qi];
            v.x += x.x; v.y += x.y; v.z += x.z; v.w += x.w;
        }
    }
    for (int base = 64; base < cnt; base += 4) { // statistically never
        int fi = base + fq;
        if (fi < cnt) {
            int flow = bk[fi];
            float4 x = ((const float4*)(ff + (size_t)flow * DD))[qi];
            v.x += x.x; v.y += x.y; v.z += x.z; v.w += x.w;
        }
    }
    // reduce across the 4 flow slots (xor 16 then 32 sums all fq groups)
    #pragma unroll
    for (int off = 16; off <= 32; off <<= 1) {
        v.x += __shfl_xor(v.x, off, 64);
        v.y += __shfl_xor(v.y, off, 64);
        v.z += __shfl_xor(v.z, off, 64);
        v.w += __shfl_xor(v.w, off, 64);
    }
    float ssq = (fq == 0) ? (v.x*v.x + v.y*v.y + v.z*v.z + v.w*v.w) : 0.f;
    float nrm = fmaxf(sqrtf(wave_sum(ssq)), 1e-12f);
    float inv = 1.f / nrm;
    __syncthreads();                            // Ws/a1s/a2s ready
    if (fq == 0)
        ((float4*)hs[wave])[qi] = make_float4(v.x*inv, v.y*inv, v.z*inv, v.w*inv);
    float whl = 0.f;
    #pragma unroll
    for (int k = 0; k < DD; ++k)
        whl = fmaf(hs[wave][k], Ws[k * DD + lane], whl);
    Wh[row * DD + lane] = whl;
    float p1 = wave_sum(whl * a1s[lane]);
    float p2 = wave_sum(whl * a2s[lane]);
    if (lane == 0) { f1[row] = p1; f2[row] = p2; }
}

// One wave per output row i: sparse masked softmax + elu(attn @ Wh).
// Neighbor indices compacted to a dense LDS list -> 4-wide MLP in phase 2.
__global__ __launch_bounds__(256) void attn_kernel(
        const unsigned int* __restrict__ mask, const float* __restrict__ f1,
        const float* __restrict__ f2, const float* __restrict__ Wh,
        float* __restrict__ out) {
    __shared__ unsigned int ms[4][MW];
    __shared__ float ps[4][NN];                 // exp(e-m), 0 where masked
    __shared__ int   jls[4][JCAP];              // compact ascending neighbor ids
    int t = threadIdx.x;
    int wave = t >> 6, lane = t & 63;
    int row = blockIdx.x * 4 + wave;            // [0, BB*NN)
    int b = row >> 10;
    const unsigned int* mrow = mask + (size_t)row * MW;
    if (lane < MW) ms[wave][lane] = mrow[lane];
    __syncthreads();
    const float* f2b = f2 + b * NN;
    const float* Whb = Wh + (size_t)(b << 10) * DD;
    float f1i = f1[row];

    // compact set bits into jls (ascending j): prefix-sum of per-word popc
    unsigned int mword = (lane < MW) ? ms[wave][lane] : 0u;
    int pc = __popc(mword);
    int x = pc;
    #pragma unroll
    for (int off = 1; off < 64; off <<= 1) {
        int y = __shfl_up(x, off, 64);
        if (lane >= off) x += y;
    }
    int cnt = __shfl(x, 63, 64);
    int o = x - pc;                             // exclusive offset
    if (cnt <= JCAP) {
        unsigned int bits = mword;
        while (bits) {
            int bidx = __ffs(bits) - 1; bits &= bits - 1;
            jls[wave][o++] = (lane << 5) + bidx;
        }
    }
    __syncthreads();

    // phase 1: leaky-relu scores (16 j's per lane), max, then exp into LDS
    float ev[16];
    float m = -INFINITY;
    #pragma unroll
    for (int tt = 0; tt < 16; ++tt) {
        int j = lane + (tt << 6);
        ev[tt] = -INFINITY;
        if (ms[wave][j >> 5] & (1u << (j & 31))) {
            float e = f1i + f2b[j];
            ev[tt] = (e >= 0.f) ? e : 0.2f * e;
            m = fmaxf(m, ev[tt]);
        }
    }
    m = wave_max(m);
    float lsum = 0.f;
    #pragma unroll
    for (int tt = 0; tt < 16; ++tt) {
        float p = (ev[tt] > -INFINITY) ? __expf(ev[tt] - m) : 0.f;
        ps[wave][lane + (tt << 6)] = p;
        lsum += p;
    }
    lsum = wave_sum(lsum);

    // phase 2: lane = feature; dense neighbor list, 4 loads in flight
    float acc = 0.f;
    if (cnt > 0 && cnt <= JCAP) {
        const int* jl = jls[wave];
        int k = 0;
        for (; k + 4 <= cnt; k += 4) {
            int j0 = jl[k], j1 = jl[k+1], j2 = jl[k+2], j3 = jl[k+3];
            float w0 = Whb[j0 * DD + lane];
            float w1 = Whb[j1 * DD + lane];
            float w2 = Whb[j2 * DD + lane];
            float w3 = Whb[j3 * DD + lane];
            acc = fmaf(ps[wave][j0], w0, acc);
            acc = fmaf(ps[wave][j1], w1, acc);
            acc = fmaf(ps[wave][j2], w2, acc);
            acc = fmaf(ps[wave][j3], w3, acc);
        }
        for (; k < cnt; ++k) {
            int j = jl[k];
            acc = fmaf(ps[wave][j], Whb[j * DD + lane], acc);
        }
        acc /= lsum;
    } else if (cnt > JCAP) {                    // formal-correctness fallback
        for (int w = 0; w < MW; ++w) {
            unsigned int bits = ms[wave][w];
            while (bits) {
                int j = (w << 5) + (__ffs(bits) - 1);
                bits &= bits - 1;
                acc = fmaf(ps[wave][j], Whb[j * DD + lane], acc);
            }
        }
        acc /= lsum;
    } else {
        // all-masked row: softmax of uniform NEG_BIG = 1/N over ALL j
        for (int j = 0; j < NN; ++j) acc += Whb[j * DD + lane];
        acc *= (1.f / NN);
    }
    out[row * DD + lane] = (acc > 0.f) ? acc : expm1f(acc);
}

extern "C" void kernel_launch(void* const* d_in, const int* in_sizes, int n_in,
                              void* d_out, int out_size, void* d_ws, size_t ws_size,
                              hipStream_t stream) {
    const float* ff      = (const float*)d_in[0];
    const int*   src_ips = (const int*)d_in[1];
    const int*   dst_ips = (const int*)d_in[2];
    // d_in[3] flow_volumes, d_in[4] emb, d_in[5..8] MLP params: adj weights are
    // products of sigmoids => strictly positive => only the >0 mask matters.
    const float* W  = (const float*)d_in[9];
    const float* a1 = (const float*)d_in[10];
    const float* a2 = (const float*)d_in[11];
    float* out = (float*)d_out;

    char* ws = (char*)d_ws;
    int* count         = (int*)ws;                           // 16 KB
    unsigned int* mask = (unsigned int*)(ws + (16 << 10));   // 512 KB (contig!)
    float* f1          = (float*)(ws + (528 << 10));         // 16 KB
    float* f2          = (float*)(ws + (544 << 10));         // 16 KB
    int* bucket        = (int*)(ws + (1 << 20));             // 4 MB
    float* Wh          = (float*)(ws + (5 << 20));           // 1 MB

    // zero count + mask in one contiguous fill (they are adjacent)
    hipMemsetAsync(count, 0, (528 << 10), stream);

    build_kernel<<<BB * SS / 256, 256, 0, stream>>>(src_ips, dst_ips, count, bucket, mask);
    gather_transform_kernel<<<BB * NN / 4, 256, 0, stream>>>(ff, count, bucket, W, a1, a2, Wh, f1, f2);
    attn_kernel<<<BB * NN / 4, 256, 0, stream>>>(mask, f1, f2, Wh, out);
}

// Round 6
// 108.199 us; speedup vs baseline: 4.6533x; 1.0169x over previous
//
#include <hip/hip_runtime.h>
#include <math.h>

#define BB 4
#define SS 16384
#define NN 1024
#define DD 64
#define MW 32    // mask words per row = NN/32
#define CAP 256  // bucket capacity per (b,node); Poisson(16) => overflow P ~ 0
#define JCAP 256 // compact neighbor-list capacity per row (fallback if exceeded)

__device__ __forceinline__ float wave_sum(float v) {
    #pragma unroll
    for (int off = 32; off > 0; off >>= 1) v += __shfl_xor(v, off, 64);
    return v;
}
__device__ __forceinline__ float wave_max(float v) {
    #pragma unroll
    for (int off = 32; off > 0; off >>= 1) v = fmaxf(v, __shfl_xor(v, off, 64));
    return v;
}

// 1 thread per flow: bucket the flow id by (b,dst), set symmetric adj bits.
__global__ __launch_bounds__(256) void build_kernel(
        const int* __restrict__ src_ips, const int* __restrict__ dst_ips,
        int* __restrict__ count, int* __restrict__ bucket,
        unsigned int* __restrict__ mask) {
    int tid = blockIdx.x * 256 + threadIdx.x;   // global flow id, [0, BB*SS)
    int b   = tid >> 14;                        // SS = 2^14
    int dst = dst_ips[tid];
    int src = src_ips[tid];
    int row = (b << 10) + dst;
    int pos = atomicAdd(count + row, 1);
    if (pos < CAP) bucket[row * CAP + pos] = tid;
    unsigned int* mb = mask + (size_t)b * NN * MW;
    atomicOr(mb + src * MW + (dst >> 5), 1u << (dst & 31));
    atomicOr(mb + dst * MW + (src >> 5), 1u << (src & 31));
}

// One wave per (b,node): float4 gather-sum of flow rows, normalize, h@W, f1, f2.
// Bucket row preloaded into registers (1 coalesced load) so the per-iteration
// chain is just shfl -> ff float4 load. Lane l: flow-slot l>>4, float4 l&15.
__global__ __launch_bounds__(256) void gather_transform_kernel(
        const float* __restrict__ ff, const int* __restrict__ count,
        const int* __restrict__ bucket, const float* __restrict__ W,
        const float* __restrict__ a1, const float* __restrict__ a2,
        float* __restrict__ Wh, float* __restrict__ f1, float* __restrict__ f2) {
    __shared__ float Ws[DD * DD];
    __shared__ float hs[4][DD];
    __shared__ float a1s[DD], a2s[DD];
    int t = threadIdx.x;
    for (int i = t; i < DD * DD / 4; i += 256)
        ((float4*)Ws)[i] = ((const float4*)W)[i];
    if (t < DD) { a1s[t] = a1[t]; a2s[t] = a2[t]; }
    int wave = t >> 6, lane = t & 63;
    int fq = lane >> 4;                         // flow slot 0..3
    int qi = lane & 15;                         // float4 index within row
    int row = blockIdx.x * 4 + wave;            // [0, BB*NN)

    int cnt = min(count[row], CAP);
    const int* bk = bucket + (size_t)row * CAP;
    int bkreg = (lane < cnt) ? bk[lane] : 0;    // whole bucket row, 1 load
    float4 v = make_float4(0.f, 0.f, 0.f, 0.f);
    int lim = min(cnt, 64);
    for (int base = 0; base < lim; base += 4) {
        int fi = base + fq;                     // <= 63 always here
        int flow = __shfl(bkreg, fi, 64);
        if (fi < lim) {
            float4 x = ((const float4*)(ff + (size_t)flow * DD))[qi];
            v.x += x.x; v.y += x.y; v.z += x.z; v.w += x.w;
        }
    }
    for (int base = 64; base < cnt; base += 4) { // statistically never
        int fi = base + fq;
        if (fi < cnt) {
            int flow = bk[fi];
            float4 x = ((const float4*)(ff + (size_t)flow * DD))[qi];
            v.x += x.x; v.y += x.y; v.z += x.z; v.w += x.w;
        }
    }
    // reduce across the 4 flow slots (xor 16 then 32 sums all fq groups)
    #pragma unroll
    for (int off = 16; off <= 32; off <<= 1) {
        v.x += __shfl_xor(v.x, off, 64);
        v.y += __shfl_xor(v.y, off, 64);
        v.z += __shfl_xor(v.z, off, 64);
        v.w += __shfl_xor(v.w, off, 64);
    }
    float ssq = (fq == 0) ? (v.x*v.x + v.y*v.y + v.z*v.z + v.w*v.w) : 0.f;
    float nrm = fmaxf(sqrtf(wave_sum(ssq)), 1e-12f);
    float inv = 1.f / nrm;
    __syncthreads();                            // Ws/a1s/a2s ready
    if (fq == 0)
        ((float4*)hs[wave])[qi] = make_float4(v.x*inv, v.y*inv, v.z*inv, v.w*inv);
    float whl = 0.f;
    #pragma unroll
    for (int k = 0; k < DD; ++k)
        whl = fmaf(hs[wave][k], Ws[k * DD + lane], whl);
    Wh[row * DD + lane] = whl;
    float p1 = wave_sum(whl * a1s[lane]);
    float p2 = wave_sum(whl * a2s[lane]);
    if (lane == 0) { f1[row] = p1; f2[row] = p2; }
}

// One wave per output row i. Compact neighbor list FIRST, then softmax only
// over neighbors (compact numerators in pls), then float4 4-row-parallel
// accumulation with a butterfly merge. Barrier-free: all LDS is same-wave.
__global__ __launch_bounds__(256) void attn_kernel(
        const unsigned int* __restrict__ mask, const float* __restrict__ f1,
        const float* __restrict__ f2, const float* __restrict__ Wh,
        float* __restrict__ out) {
    __shared__ int   jls[4][JCAP];              // compact ascending neighbor ids
    __shared__ float pls[4][JCAP];              // exp(e-m) per compact slot
    int t = threadIdx.x;
    int wave = t >> 6, lane = t & 63;
    int row = blockIdx.x * 4 + wave;            // [0, BB*NN)
    int b = row >> 10;
    unsigned int mword = (lane < MW) ? mask[(size_t)row * MW + lane] : 0u;
    const float* f2b = f2 + b * NN;
    const float* Whb = Wh + (size_t)(b << 10) * DD;
    float f1i = f1[row];

    // compact set bits into jls (ascending j): prefix-sum of per-word popc
    int pc = __popc(mword);
    int x = pc;
    #pragma unroll
    for (int off = 1; off < 64; off <<= 1) {
        int y = __shfl_up(x, off, 64);
        if (lane >= off) x += y;
    }
    int cnt = __shfl(x, 63, 64);
    int o = x - pc;                             // exclusive offset
    if (cnt <= JCAP) {
        unsigned int bits = mword;
        while (bits) {
            int bidx = __ffs(bits) - 1; bits &= bits - 1;
            jls[wave][o++] = (lane << 5) + bidx;
        }
    }

    int fq = lane >> 4;                         // neighbor slot 0..3
    int qi = lane & 15;                         // float4 index within Wh row

    if (cnt > 0 && cnt <= JCAP) {
        // softmax over the cnt neighbors only (cnt <= 64 typical: 1 iteration)
        float m = -INFINITY;
        for (int k = lane; k < cnt; k += 64) {
            int j = jls[wave][k];
            float e = f1i + f2b[j];
            e = (e >= 0.f) ? e : 0.2f * e;
            m = fmaxf(m, e);
        }
        m = wave_max(m);
        float lsum = 0.f;
        for (int k = lane; k < cnt; k += 64) {
            int j = jls[wave][k];
            float e = f1i + f2b[j];
            e = (e >= 0.f) ? e : 0.2f * e;
            float p = __expf(e - m);
            pls[wave][k] = p;
            lsum += p;
        }
        lsum = wave_sum(lsum);
        // 4 neighbor rows per iteration, float4 loads (1 KiB/instr coalesced)
        float4 acc = make_float4(0.f, 0.f, 0.f, 0.f);
        for (int k = fq; k < cnt; k += 4) {
            int j   = jls[wave][k];
            float p = pls[wave][k];
            float4 w = ((const float4*)(Whb + (size_t)j * DD))[qi];
            acc.x = fmaf(p, w.x, acc.x);
            acc.y = fmaf(p, w.y, acc.y);
            acc.z = fmaf(p, w.z, acc.z);
            acc.w = fmaf(p, w.w, acc.w);
        }
        #pragma unroll
        for (int off = 16; off <= 32; off <<= 1) {
            acc.x += __shfl_xor(acc.x, off, 64);
            acc.y += __shfl_xor(acc.y, off, 64);
            acc.z += __shfl_xor(acc.z, off, 64);
            acc.w += __shfl_xor(acc.w, off, 64);
        }
        if (fq == 0) {
            float inv = 1.f / lsum;
            float4 r;
            r.x = acc.x * inv; r.y = acc.y * inv;
            r.z = acc.z * inv; r.w = acc.w * inv;
            r.x = (r.x > 0.f) ? r.x : expm1f(r.x);
            r.y = (r.y > 0.f) ? r.y : expm1f(r.y);
            r.z = (r.z > 0.f) ? r.z : expm1f(r.z);
            r.w = (r.w > 0.f) ? r.w : expm1f(r.w);
            ((float4*)(out + (size_t)row * DD))[qi] = r;
        }
    } else if (cnt == 0) {
        // all-masked row: softmax of uniform NEG_BIG = 1/N over ALL j
        float4 acc = make_float4(0.f, 0.f, 0.f, 0.f);
        for (int k = fq; k < NN; k += 4) {
            float4 w = ((const float4*)(Whb + (size_t)k * DD))[qi];
            acc.x += w.x; acc.y += w.y; acc.z += w.z; acc.w += w.w;
        }
        #pragma unroll
        for (int off = 16; off <= 32; off <<= 1) {
            acc.x += __shfl_xor(acc.x, off, 64);
            acc.y += __shfl_xor(acc.y, off, 64);
            acc.z += __shfl_xor(acc.z, off, 64);
            acc.w += __shfl_xor(acc.w, off, 64);
        }
        if (fq == 0) {
            float4 r;
            r.x = acc.x * (1.f / NN); r.y = acc.y * (1.f / NN);
            r.z = acc.z * (1.f / NN); r.w = acc.w * (1.f / NN);
            r.x = (r.x > 0.f) ? r.x : expm1f(r.x);
            r.y = (r.y > 0.f) ? r.y : expm1f(r.y);
            r.z = (r.z > 0.f) ? r.z : expm1f(r.z);
            r.w = (r.w > 0.f) ? r.w : expm1f(r.w);
            ((float4*)(out + (size_t)row * DD))[qi] = r;
        }
    } else {
        // cnt > JCAP: full-scan fallback (statistically never)
        float m = -INFINITY;
        for (int tt = 0; tt < 16; ++tt) {
            int j = lane + (tt << 6);
            unsigned int wv = __shfl(mword, j >> 5, 64);
            if (wv & (1u << (j & 31))) {
                float e = f1i + f2b[j];
                e = (e >= 0.f) ? e : 0.2f * e;
                m = fmaxf(m, e);
            }
        }
        m = wave_max(m);
        float lsum = 0.f;
        for (int tt = 0; tt < 16; ++tt) {
            int j = lane + (tt << 6);
            unsigned int wv = __shfl(mword, j >> 5, 64);
            if (wv & (1u << (j & 31))) {
                float e = f1i + f2b[j];
                e = (e >= 0.f) ? e : 0.2f * e;
                lsum += __expf(e - m);
            }
        }
        lsum = wave_sum(lsum);
        float acc = 0.f;
        for (int w = 0; w < MW; ++w) {
            unsigned int bits = __shfl(mword, w, 64);
            while (bits) {
                int j = (w << 5) + (__ffs(bits) - 1);
                bits &= bits - 1;
                float e = f1i + f2b[j];
                e = (e >= 0.f) ? e : 0.2f * e;
                acc = fmaf(__expf(e - m), Whb[(size_t)j * DD + lane], acc);
            }
        }
        acc /= lsum;
        out[(size_t)row * DD + lane] = (acc > 0.f) ? acc : expm1f(acc);
    }
}

extern "C" void kernel_launch(void* const* d_in, const int* in_sizes, int n_in,
                              void* d_out, int out_size, void* d_ws, size_t ws_size,
                              hipStream_t stream) {
    const float* ff      = (const float*)d_in[0];
    const int*   src_ips = (const int*)d_in[1];
    const int*   dst_ips = (const int*)d_in[2];
    // d_in[3] flow_volumes, d_in[4] emb, d_in[5..8] MLP params: adj weights are
    // products of sigmoids => strictly positive => only the >0 mask matters.
    const float* W  = (const float*)d_in[9];
    const float* a1 = (const float*)d_in[10];
    const float* a2 = (const float*)d_in[11];
    float* out = (float*)d_out;

    char* ws = (char*)d_ws;
    int* count         = (int*)ws;                           // 16 KB
    unsigned int* mask = (unsigned int*)(ws + (16 << 10));   // 512 KB (contig!)
    float* f1          = (float*)(ws + (528 << 10));         // 16 KB
    float* f2          = (float*)(ws + (544 << 10));         // 16 KB
    int* bucket        = (int*)(ws + (1 << 20));             // 4 MB
    float* Wh          = (float*)(ws + (5 << 20));           // 1 MB

    // zero count + mask in one contiguous fill (they are adjacent)
    hipMemsetAsync(count, 0, (528 << 10), stream);

    build_kernel<<<BB * SS / 256, 256, 0, stream>>>(src_ips, dst_ips, count, bucket, mask);
    gather_transform_kernel<<<BB * NN / 4, 256, 0, stream>>>(ff, count, bucket, W, a1, a2, Wh, f1, f2);
    attn_kernel<<<BB * NN / 4, 256, 0, stream>>>(mask, f1, f2, Wh, out);
}

// Round 7
// 103.637 us; speedup vs baseline: 4.8581x; 1.0440x over previous
//
#include <hip/hip_runtime.h>
#include <math.h>

#define BB 4
#define SS 16384
#define NN 1024
#define DD 64
#define MW 32    // bitmap words per row = NN/32
#define CAP 256  // bucket capacity per (b,node); Poisson(16) => overflow P ~ 0
#define JCAP 512 // compact neighbor-list capacity; union of two CAP lists <= 512

__device__ __forceinline__ float wave_sum(float v) {
    #pragma unroll
    for (int off = 32; off > 0; off >>= 1) v += __shfl_xor(v, off, 64);
    return v;
}
__device__ __forceinline__ float wave_max(float v) {
    #pragma unroll
    for (int off = 32; off > 0; off >>= 1) v = fmaxf(v, __shfl_xor(v, off, 64));
    return v;
}

// 1 thread per flow: dual CSR buckets. bucket_d keyed by (b,dst) stores
// tid|src<<16 (tid<65536, src<1024); bucket_s keyed by (b,src) stores dst.
// 2 atomics/flow (vs 3 with a global mask) and no scattered atomicOr.
__global__ __launch_bounds__(256) void build_kernel(
        const int* __restrict__ src_ips, const int* __restrict__ dst_ips,
        int* __restrict__ cntd, int* __restrict__ cnts,
        int* __restrict__ bucket_d, int* __restrict__ bucket_s) {
    int tid = blockIdx.x * 256 + threadIdx.x;   // global flow id, [0, BB*SS)
    int b   = tid >> 14;                        // SS = 2^14
    int dst = dst_ips[tid];
    int src = src_ips[tid];
    int rd = (b << 10) + dst;
    int rs = (b << 10) + src;
    int pd = atomicAdd(cntd + rd, 1);
    if (pd < CAP) bucket_d[rd * CAP + pd] = tid | (src << 16);
    int ps = atomicAdd(cnts + rs, 1);
    if (ps < CAP) bucket_s[rs * CAP + ps] = dst;
}

// One wave per (b,node): float4 gather-sum of flow rows, normalize, h@W, f1, f2.
// Bucket row preloaded into registers; 8 flows (2x float4 accs) per iteration.
__global__ __launch_bounds__(256) void gather_transform_kernel(
        const float* __restrict__ ff, const int* __restrict__ cntd,
        const int* __restrict__ bucket_d, const float* __restrict__ W,
        const float* __restrict__ a1, const float* __restrict__ a2,
        float* __restrict__ Wh, float* __restrict__ f1, float* __restrict__ f2) {
    __shared__ float Ws[DD * DD];
    __shared__ float hs[4][DD];
    __shared__ float a1s[DD], a2s[DD];
    int t = threadIdx.x;
    for (int i = t; i < DD * DD / 4; i += 256)
        ((float4*)Ws)[i] = ((const float4*)W)[i];
    if (t < DD) { a1s[t] = a1[t]; a2s[t] = a2[t]; }
    int wave = t >> 6, lane = t & 63;
    int fq = lane >> 4;                         // flow slot 0..3
    int qi = lane & 15;                         // float4 index within row
    int row = blockIdx.x * 4 + wave;            // [0, BB*NN)

    int cnt = min(cntd[row], CAP);
    const int* bk = bucket_d + (size_t)row * CAP;
    int bkreg = (lane < cnt) ? bk[lane] : 0;    // whole bucket row, 1 load
    float4 v0 = make_float4(0.f, 0.f, 0.f, 0.f);
    float4 v1 = make_float4(0.f, 0.f, 0.f, 0.f);
    int lim = min(cnt, 64);
    for (int base = 0; base < lim; base += 8) {
        int fi0 = base + fq;                    // <= 59
        int fi1 = base + 4 + fq;                // <= 63
        int w0 = __shfl(bkreg, fi0, 64);
        int w1 = __shfl(bkreg, fi1, 64);
        if (fi0 < lim) {
            float4 x = ((const float4*)(ff + (size_t)(w0 & 0xFFFF) * DD))[qi];
            v0.x += x.x; v0.y += x.y; v0.z += x.z; v0.w += x.w;
        }
        if (fi1 < lim) {
            float4 x = ((const float4*)(ff + (size_t)(w1 & 0xFFFF) * DD))[qi];
            v1.x += x.x; v1.y += x.y; v1.z += x.z; v1.w += x.w;
        }
    }
    for (int base = 64; base < cnt; base += 4) { // statistically never
        int fi = base + fq;
        if (fi < cnt) {
            int flow = bk[fi] & 0xFFFF;
            float4 x = ((const float4*)(ff + (size_t)flow * DD))[qi];
            v0.x += x.x; v0.y += x.y; v0.z += x.z; v0.w += x.w;
        }
    }
    float4 v = make_float4(v0.x + v1.x, v0.y + v1.y, v0.z + v1.z, v0.w + v1.w);
    // reduce across the 4 flow slots (xor 16 then 32 sums all fq groups)
    #pragma unroll
    for (int off = 16; off <= 32; off <<= 1) {
        v.x += __shfl_xor(v.x, off, 64);
        v.y += __shfl_xor(v.y, off, 64);
        v.z += __shfl_xor(v.z, off, 64);
        v.w += __shfl_xor(v.w, off, 64);
    }
    float ssq = (fq == 0) ? (v.x*v.x + v.y*v.y + v.z*v.z + v.w*v.w) : 0.f;
    float nrm = fmaxf(sqrtf(wave_sum(ssq)), 1e-12f);
    float inv = 1.f / nrm;
    __syncthreads();                            // Ws/a1s/a2s ready
    if (fq == 0)
        ((float4*)hs[wave])[qi] = make_float4(v.x*inv, v.y*inv, v.z*inv, v.w*inv);
    float whl = 0.f;
    #pragma unroll
    for (int k = 0; k < DD; ++k)
        whl = fmaf(hs[wave][k], Ws[k * DD + lane], whl);
    Wh[row * DD + lane] = whl;
    float p1 = wave_sum(whl * a1s[lane]);
    float p2 = wave_sum(whl * a2s[lane]);
    if (lane == 0) { f1[row] = p1; f2[row] = p2; }
}

// One wave per output row i. Neighbor set = union(srcs of in-flows, dsts of
// out-flows) via per-wave LDS bitmap (same-wave DS ops are ordered -> no
// barrier). Compact ascending, softmax over neighbors only, float4 8-wide acc.
__global__ __launch_bounds__(256) void attn_kernel(
        const int* __restrict__ cntd, const int* __restrict__ cnts,
        const int* __restrict__ bucket_d, const int* __restrict__ bucket_s,
        const float* __restrict__ f1, const float* __restrict__ f2,
        const float* __restrict__ Wh, float* __restrict__ out) {
    __shared__ unsigned int bms[4][MW];         // per-wave neighbor bitmap
    __shared__ int   jls[4][JCAP];              // compact ascending neighbor ids
    __shared__ float pls[4][JCAP];              // exp(e-m) per compact slot
    int t = threadIdx.x;
    int wave = t >> 6, lane = t & 63;
    int row = blockIdx.x * 4 + wave;            // [0, BB*NN)
    int b = row >> 10;
    if (lane < MW) bms[wave][lane] = 0u;
    int c1 = min(cntd[row], CAP);
    int c2 = min(cnts[row], CAP);
    const int* bd = bucket_d + (size_t)row * CAP;
    const int* bs = bucket_s + (size_t)row * CAP;
    for (int k = lane; k < c1; k += 64) {
        int cand = (bd[k] >> 16) & 0x3FF;       // src of in-flow
        atomicOr(&bms[wave][cand >> 5], 1u << (cand & 31));
    }
    for (int k = lane; k < c2; k += 64) {
        int cand = bs[k] & 0x3FF;               // dst of out-flow
        atomicOr(&bms[wave][cand >> 5], 1u << (cand & 31));
    }
    unsigned int mword = (lane < MW) ? bms[wave][lane] : 0u;
    const float* f2b = f2 + b * NN;
    const float* Whb = Wh + (size_t)(b << 10) * DD;
    float f1i = f1[row];

    // compact set bits into jls (ascending j): prefix-sum of per-word popc
    int pc = __popc(mword);
    int x = pc;
    #pragma unroll
    for (int off = 1; off < 64; off <<= 1) {
        int y = __shfl_up(x, off, 64);
        if (lane >= off) x += y;
    }
    int cnt = __shfl(x, 63, 64);                // <= c1+c2 <= 512 = JCAP always
    int o = x - pc;                             // exclusive offset
    {
        unsigned int bits = mword;
        while (bits) {
            int bidx = __ffs(bits) - 1; bits &= bits - 1;
            jls[wave][o++] = (lane << 5) + bidx;
        }
    }

    int fq = lane >> 4;                         // neighbor slot 0..3
    int qi = lane & 15;                         // float4 index within Wh row

    if (cnt > 0) {
        // softmax over the cnt neighbors only (cnt <= 64 typical: 1 iteration)
        float m = -INFINITY;
        for (int k = lane; k < cnt; k += 64) {
            int j = jls[wave][k];
            float e = f1i + f2b[j];
            e = (e >= 0.f) ? e : 0.2f * e;
            m = fmaxf(m, e);
        }
        m = wave_max(m);
        float lsum = 0.f;
        for (int k = lane; k < cnt; k += 64) {
            int j = jls[wave][k];
            float e = f1i + f2b[j];
            e = (e >= 0.f) ? e : 0.2f * e;
            float p = __expf(e - m);
            pls[wave][k] = p;
            lsum += p;
        }
        lsum = wave_sum(lsum);
        // 8 neighbor rows per iteration, float4 loads, two accumulators
        float4 a0 = make_float4(0.f, 0.f, 0.f, 0.f);
        float4 a1 = make_float4(0.f, 0.f, 0.f, 0.f);
        for (int k = fq; k < cnt; k += 8) {
            int j0   = jls[wave][k];
            float p0 = pls[wave][k];
            float4 w0 = ((const float4*)(Whb + (size_t)j0 * DD))[qi];
            a0.x = fmaf(p0, w0.x, a0.x);
            a0.y = fmaf(p0, w0.y, a0.y);
            a0.z = fmaf(p0, w0.z, a0.z);
            a0.w = fmaf(p0, w0.w, a0.w);
            int k1 = k + 4;
            if (k1 < cnt) {
                int j1   = jls[wave][k1];
                float p1 = pls[wave][k1];
                float4 w1 = ((const float4*)(Whb + (size_t)j1 * DD))[qi];
                a1.x = fmaf(p1, w1.x, a1.x);
                a1.y = fmaf(p1, w1.y, a1.y);
                a1.z = fmaf(p1, w1.z, a1.z);
                a1.w = fmaf(p1, w1.w, a1.w);
            }
        }
        float4 acc = make_float4(a0.x + a1.x, a0.y + a1.y,
                                 a0.z + a1.z, a0.w + a1.w);
        #pragma unroll
        for (int off = 16; off <= 32; off <<= 1) {
            acc.x += __shfl_xor(acc.x, off, 64);
            acc.y += __shfl_xor(acc.y, off, 64);
            acc.z += __shfl_xor(acc.z, off, 64);
            acc.w += __shfl_xor(acc.w, off, 64);
        }
        if (fq == 0) {
            float inv = 1.f / lsum;
            float4 r;
            r.x = acc.x * inv; r.y = acc.y * inv;
            r.z = acc.z * inv; r.w = acc.w * inv;
            r.x = (r.x > 0.f) ? r.x : expm1f(r.x);
            r.y = (r.y > 0.f) ? r.y : expm1f(r.y);
            r.z = (r.z > 0.f) ? r.z : expm1f(r.z);
            r.w = (r.w > 0.f) ? r.w : expm1f(r.w);
            ((float4*)(out + (size_t)row * DD))[qi] = r;
        }
    } else {
        // isolated node: softmax of uniform NEG_BIG = 1/N over ALL j
        float4 acc = make_float4(0.f, 0.f, 0.f, 0.f);
        for (int k = fq; k < NN; k += 4) {
            float4 w = ((const float4*)(Whb + (size_t)k * DD))[qi];
            acc.x += w.x; acc.y += w.y; acc.z += w.z; acc.w += w.w;
        }
        #pragma unroll
        for (int off = 16; off <= 32; off <<= 1) {
            acc.x += __shfl_xor(acc.x, off, 64);
            acc.y += __shfl_xor(acc.y, off, 64);
            acc.z += __shfl_xor(acc.z, off, 64);
            acc.w += __shfl_xor(acc.w, off, 64);
        }
        if (fq == 0) {
            float4 r;
            r.x = acc.x * (1.f / NN); r.y = acc.y * (1.f / NN);
            r.z = acc.z * (1.f / NN); r.w = acc.w * (1.f / NN);
            r.x = (r.x > 0.f) ? r.x : expm1f(r.x);
            r.y = (r.y > 0.f) ? r.y : expm1f(r.y);
            r.z = (r.z > 0.f) ? r.z : expm1f(r.z);
            r.w = (r.w > 0.f) ? r.w : expm1f(r.w);
            ((float4*)(out + (size_t)row * DD))[qi] = r;
        }
    }
}

extern "C" void kernel_launch(void* const* d_in, const int* in_sizes, int n_in,
                              void* d_out, int out_size, void* d_ws, size_t ws_size,
                              hipStream_t stream) {
    const float* ff      = (const float*)d_in[0];
    const int*   src_ips = (const int*)d_in[1];
    const int*   dst_ips = (const int*)d_in[2];
    // d_in[3] flow_volumes, d_in[4] emb, d_in[5..8] MLP params: adj weights are
    // products of sigmoids => strictly positive => only the >0 mask matters.
    const float* W  = (const float*)d_in[9];
    const float* a1 = (const float*)d_in[10];
    const float* a2 = (const float*)d_in[11];
    float* out = (float*)d_out;

    char* ws = (char*)d_ws;
    int* cntd       = (int*)ws;                          // 16 KB
    int* cnts       = (int*)(ws + (16 << 10));           // 16 KB (contig w/ cntd)
    float* f1       = (float*)(ws + (32 << 10));         // 16 KB
    float* f2       = (float*)(ws + (48 << 10));         // 16 KB
    int* bucket_d   = (int*)(ws + (1 << 20));            // 4 MB
    int* bucket_s   = (int*)(ws + (5 << 20));            // 4 MB
    float* Wh       = (float*)(ws + (9 << 20));          // 1 MB

    // zero both count arrays in one contiguous 32 KB fill
    hipMemsetAsync(cntd, 0, (32 << 10), stream);

    build_kernel<<<BB * SS / 256, 256, 0, stream>>>(src_ips, dst_ips,
                                                    cntd, cnts, bucket_d, bucket_s);
    gather_transform_kernel<<<BB * NN / 4, 256, 0, stream>>>(ff, cntd, bucket_d,
                                                             W, a1, a2, Wh, f1, f2);
    attn_kernel<<<BB * NN / 4, 256, 0, stream>>>(cntd, cnts, bucket_d, bucket_s,
                                                 f1, f2, Wh, out);
}